// Round 1
// baseline (425.563 us; speedup 1.0000x reference)
//
#include <hip/hip_runtime.h>

// ---------------------------------------------------------------------------
// Fusion_12867722019048: trimodal fusion MLP forward, B=65536, IN=64, H=16.
//
// Math identity used: all maxpooled quantities are products of sigmoids (>0),
// so maxpool of outer products factorizes:
//   fusion[a*32+m*8+l] = A[a] * V2[m] * L[l]
// where A = pairwise max of x_h (8), V2 = quad max of y_h (4),
// L = pairwise max of z_h (8).
//
// One thread per sample. Weights read via wave-uniform scalar loads.
// Wf1/Wfp1/Wng pre-transposed into d_ws so per-feature weight rows are
// contiguous. LDS used only as per-thread scratch for dynamically-indexed
// values (layout [idx][tid] -> consecutive lanes hit consecutive banks,
// conflict-free, no __syncthreads needed).
// ---------------------------------------------------------------------------

#define NT 256  // threads per block; grid = 256 blocks -> 1 wave/SIMD

__device__ __forceinline__ float fast_sigmoid(float x) {
    return __builtin_amdgcn_rcpf(1.0f + __expf(-x));
}
__device__ __forceinline__ float gate(float x, float rm) {
    // eval-mode normGate2: x * sigmoid(|x - rm|)
    return x * fast_sigmoid(fabsf(x - rm));
}
__device__ __forceinline__ float lrelu(float x) {
    return x >= 0.0f ? x : 0.01f * x;
}

__device__ __forceinline__ void load64(const float* __restrict__ p, float x[64]) {
    const float4* p4 = reinterpret_cast<const float4*>(p);
    #pragma unroll
    for (int j = 0; j < 16; ++j) {
        float4 t = p4[j];
        x[4*j+0] = t.x; x[4*j+1] = t.y; x[4*j+2] = t.z; x[4*j+3] = t.w;
    }
}

// 16x64 gemv (row-major W) + bias + sigmoid + pairwise max -> out8
__device__ __forceinline__ void proj8(const float* __restrict__ W,
                                      const float* __restrict__ b,
                                      const float x[64], float out8[8]) {
    #pragma unroll
    for (int r = 0; r < 8; ++r) {
        float h2[2];
        #pragma unroll
        for (int u = 0; u < 2; ++u) {
            const int o = 2*r + u;
            const float* w = W + o*64;  // uniform address -> s_load
            float s0 = 0.f, s1 = 0.f, s2 = 0.f, s3 = 0.f;
            #pragma unroll
            for (int j = 0; j < 64; j += 4) {
                s0 = fmaf(x[j+0], w[j+0], s0);
                s1 = fmaf(x[j+1], w[j+1], s1);
                s2 = fmaf(x[j+2], w[j+2], s2);
                s3 = fmaf(x[j+3], w[j+3], s3);
            }
            h2[u] = fast_sigmoid((s0+s1) + (s2+s3) + b[o]);
        }
        out8[r] = fmaxf(h2[0], h2[1]);
    }
}

// acc[k] = bias[k] + sum_{a,m,l} X[a]*Y2[m]*Z[l] * WT[(a*32+m*8+l)*64 + k]
// XY products staged through LDS so the 32-iteration loop can stay dynamic
// (no dynamic register-array indexing -> no scratch spill).
__device__ __forceinline__ void fusion_gemv(const float* __restrict__ WT,
                                            const float* __restrict__ bias,
                                            const float X[8], const float Y2[4],
                                            const float Z[8],
                                            float* __restrict__ ldscol,
                                            float acc[64]) {
    #pragma unroll
    for (int k = 0; k < 64; ++k) acc[k] = bias[k];
    #pragma unroll
    for (int aa = 0; aa < 8; ++aa)
        #pragma unroll
        for (int mm = 0; mm < 4; ++mm)
            ldscol[(aa*4 + mm) * NT] = X[aa] * Y2[mm];
    #pragma unroll 1
    for (int q = 0; q < 32; ++q) {
        const float t = ldscol[q * NT];
        const float* w = WT + q * 8 * 64;  // uniform -> s_load_dwordx16 batches
        #pragma unroll
        for (int ll = 0; ll < 8; ++ll) {
            const float f = t * Z[ll];
            #pragma unroll
            for (int k = 0; k < 64; ++k)
                acc[k] = fmaf(f, w[ll*64 + k], acc[k]);
        }
    }
}

// h[k] += sum_{i<64} ldscol[i] * WngT[(row_off+i)*64 + k]
__device__ __forceinline__ void ng_accum(const float* __restrict__ WngT, int row_off,
                                         const float* __restrict__ ldscol, float h[64]) {
    #pragma unroll 1
    for (int i = 0; i < 64; ++i) {
        const float gi = ldscol[i * NT];
        const float* w = WngT + (row_off + i) * 64;  // uniform -> s_load
        #pragma unroll
        for (int k = 0; k < 64; ++k)
            h[k] = fmaf(gi, w[k], h[k]);
    }
}

__global__ __launch_bounds__(NT, 1)
void fused_fwd(const float* __restrict__ a,  const float* __restrict__ v,
               const float* __restrict__ l,  const float* __restrict__ pa,
               const float* __restrict__ pv, const float* __restrict__ pl,
               const float* __restrict__ mean,
               const float* __restrict__ Wa,  const float* __restrict__ ba,
               const float* __restrict__ Wv,  const float* __restrict__ bv,
               const float* __restrict__ Wl,  const float* __restrict__ bl,
               const float* __restrict__ Wap, const float* __restrict__ bap,
               const float* __restrict__ Wvp, const float* __restrict__ bvp,
               const float* __restrict__ Wlp, const float* __restrict__ blp,
               const float* __restrict__ bf1, const float* __restrict__ bfp1,
               const float* __restrict__ bng,
               const float* __restrict__ rm1, const float* __restrict__ rm2,
               const float* __restrict__ WfT, const float* __restrict__ WfpT,
               const float* __restrict__ WngT,
               float* __restrict__ out) {
    __shared__ float lds[64 * NT];  // 64 KiB, per-thread scratch columns
    const int tid = threadIdx.x;
    const int gidx = blockIdx.x * NT + tid;
    float* ldscol = &lds[tid];
    const size_t base = (size_t)gidx * 64;

    float x[64];
    float X[8], Y2[4], Z[8];
    float acc[64];

    // ---------------- fusion_2 path (p_a, p_v, p_l) ----------------
    load64(pa + base, x);
    proj8(Wap, bap, x, X);
    load64(pv + base, x);
    {
        float Y[8];
        proj8(Wvp, bvp, x, Y);
        #pragma unroll
        for (int m = 0; m < 4; ++m) Y2[m] = fmaxf(Y[2*m], Y[2*m+1]);
    }
    load64(pl + base, x);
    proj8(Wlp, blp, x, Z);
    fusion_gemv(WfpT, bfp1, X, Y2, Z, ldscol, acc);

    // leaky_relu -> fusion_2; gate with rm1[0:64]; stage to LDS
    #pragma unroll
    for (int i = 0; i < 64; ++i)
        ldscol[i * NT] = gate(lrelu(acc[i]), rm1[i]);

    // h = bng + g @ WngT  (first 64 rows = fusion_2 part)
    float h[64];
    #pragma unroll
    for (int k = 0; k < 64; ++k) h[k] = bng[k];
    ng_accum(WngT, 0, ldscol, h);

    // gated mean -> LDS (rows 64..127 of Wng input), accumulate
    load64(mean + base, x);
    #pragma unroll
    for (int i = 0; i < 64; ++i)
        ldscol[i * NT] = gate(x[i], rm1[64 + i]);
    ng_accum(WngT, 64, ldscol, h);

    // ---------------- fusion_1 path (a, v, l) ----------------
    load64(a + base, x);
    proj8(Wa, ba, x, X);
    load64(v + base, x);
    {
        float Y[8];
        proj8(Wv, bv, x, Y);
        #pragma unroll
        for (int m = 0; m < 4; ++m) Y2[m] = fmaxf(Y[2*m], Y[2*m+1]);
    }
    load64(l + base, x);
    proj8(Wl, bl, x, Z);
    fusion_gemv(WfT, bf1, X, Y2, Z, ldscol, acc);

    // ---------------- epilogue: out = gate(concat(h, lrelu(fusion_1)), rm2)
    float4* out4 = reinterpret_cast<float4*>(out + (size_t)gidx * 128);
    #pragma unroll
    for (int k = 0; k < 16; ++k) {
        float4 o;
        o.x = gate(h[4*k+0], rm2[4*k+0]);
        o.y = gate(h[4*k+1], rm2[4*k+1]);
        o.z = gate(h[4*k+2], rm2[4*k+2]);
        o.w = gate(h[4*k+3], rm2[4*k+3]);
        out4[k] = o;
    }
    #pragma unroll
    for (int k = 0; k < 16; ++k) {
        float4 o;
        o.x = gate(lrelu(acc[4*k+0]), rm2[64 + 4*k+0]);
        o.y = gate(lrelu(acc[4*k+1]), rm2[64 + 4*k+1]);
        o.z = gate(lrelu(acc[4*k+2]), rm2[64 + 4*k+2]);
        o.w = gate(lrelu(acc[4*k+3]), rm2[64 + 4*k+3]);
        out4[16 + k] = o;
    }
}

// Pre-transpose Wf1 [64,256] -> WfT [256,64], Wfp1 likewise, Wng [64,128] ->
// WngT [128,64] so the main kernel's scalar weight loads are contiguous.
__global__ void transpose_w(const float* __restrict__ Wf1,
                            const float* __restrict__ Wfp1,
                            const float* __restrict__ Wng,
                            float* __restrict__ ws) {
    const int idx = blockIdx.x * 256 + threadIdx.x;
    if (idx < 16384) {
        const int j = idx >> 6, k = idx & 63;
        ws[idx] = Wf1[k * 256 + j];
    } else if (idx < 32768) {
        const int t = idx - 16384;
        const int j = t >> 6, k = t & 63;
        ws[16384 + t] = Wfp1[k * 256 + j];
    } else if (idx < 40960) {
        const int t = idx - 32768;
        const int i = t >> 6, k = t & 63;
        ws[32768 + t] = Wng[k * 128 + i];
    }
}

extern "C" void kernel_launch(void* const* d_in, const int* in_sizes, int n_in,
                              void* d_out, int out_size, void* d_ws, size_t ws_size,
                              hipStream_t stream) {
    const float* a    = (const float*)d_in[0];
    const float* v    = (const float*)d_in[1];
    const float* l    = (const float*)d_in[2];
    const float* pa   = (const float*)d_in[3];
    const float* pv   = (const float*)d_in[4];
    const float* pl   = (const float*)d_in[5];
    const float* mean = (const float*)d_in[6];
    const float* Wa   = (const float*)d_in[7];
    const float* ba   = (const float*)d_in[8];
    const float* Wv   = (const float*)d_in[9];
    const float* bv   = (const float*)d_in[10];
    const float* Wl   = (const float*)d_in[11];
    const float* bl   = (const float*)d_in[12];
    const float* Wap  = (const float*)d_in[13];
    const float* bap  = (const float*)d_in[14];
    const float* Wvp  = (const float*)d_in[15];
    const float* bvp  = (const float*)d_in[16];
    const float* Wlp  = (const float*)d_in[17];
    const float* blp  = (const float*)d_in[18];
    const float* Wf1  = (const float*)d_in[19];
    const float* bf1  = (const float*)d_in[20];
    const float* Wfp1 = (const float*)d_in[21];
    const float* bfp1 = (const float*)d_in[22];
    const float* Wng  = (const float*)d_in[23];
    const float* bng  = (const float*)d_in[24];
    const float* rm1  = (const float*)d_in[25];
    const float* rm2  = (const float*)d_in[26];

    float* ws = (float*)d_ws;  // needs 40960 floats = 160 KiB

    transpose_w<<<160, 256, 0, stream>>>(Wf1, Wfp1, Wng, ws);
    fused_fwd<<<256, NT, 0, stream>>>(a, v, l, pa, pv, pl, mean,
                                      Wa, ba, Wv, bv, Wl, bl,
                                      Wap, bap, Wvp, bvp, Wlp, blp,
                                      bf1, bfp1, bng, rm1, rm2,
                                      ws, ws + 16384, ws + 32768,
                                      (float*)d_out);
}

// Round 2
// 262.468 us; speedup vs baseline: 1.6214x; 1.6214x over previous
//
#include <hip/hip_runtime.h>

// ---------------------------------------------------------------------------
// Fusion_12867722019048: trimodal fusion MLP forward, B=65536, IN=64, H=16.
//
// Math identity (verified passing in round 1): all maxpooled values are
// products of sigmoids (>0), so the pools factorize:
//   fusion[a*32+m*8+l] = X[a] * Y2[m] * Z[l]
// with X = pairwise max of x_h (8), Y2 = quad max of y_h (4),
// Z = pairwise max of z_h (8).
//
// Round-2 restructure: round 1 had 1 thread/sample -> 1024 waves -> 1
// wave/SIMD -> latency-bound (VALUBusy 17.7%). Now 4 waves cooperate on 64
// samples: wave w owns output columns [16w,16w+16) of every 64-wide gemv and
// rows [4w,4w+4) of every 16-row projection. 4096 waves -> 4 waves/SIMD.
// wq comes from readfirstlane so ALL weight addresses are wave-uniform ->
// scalar s_load path (no VALU/VMEM cost). Per-sample shared values go through
// LDS columns [slot][sample]: addr = slot*64+lane -> 2 lanes/bank = free.
// ---------------------------------------------------------------------------

#define NT 256
#define NS 64   // samples per block (= lanes per wave)

__device__ __forceinline__ float fast_sigmoid(float x) {
    return __builtin_amdgcn_rcpf(1.0f + __expf(-x));
}
__device__ __forceinline__ float gate(float x, float rm) {
    // eval-mode normGate2: x * sigmoid(|x - rm|)
    return x * fast_sigmoid(fabsf(x - rm));
}
__device__ __forceinline__ float lrelu(float x) {
    return x >= 0.0f ? x : 0.01f * x;
}

// rows [r0, r0+4) of sigmoid(W(16x64) @ x + b) for this lane's sample.
// W, b wave-uniform (s_load); x per-lane (coalesced float4 loads).
__device__ __forceinline__ void proj4(const float* __restrict__ W,
                                      const float* __restrict__ b,
                                      const float* __restrict__ xrow,
                                      int r0, float o4[4]) {
    float s[4] = {0.f, 0.f, 0.f, 0.f};
    const float4* x4 = reinterpret_cast<const float4*>(xrow);
    #pragma unroll
    for (int c = 0; c < 16; ++c) {
        float4 t = x4[c];
        #pragma unroll
        for (int o = 0; o < 4; ++o) {
            const float* w = W + (r0 + o) * 64 + c * 4;  // uniform -> s_load
            s[o] = fmaf(t.x, w[0], s[o]);
            s[o] = fmaf(t.y, w[1], s[o]);
            s[o] = fmaf(t.z, w[2], s[o]);
            s[o] = fmaf(t.w, w[3], s[o]);
        }
    }
    #pragma unroll
    for (int o = 0; o < 4; ++o) o4[o] = fast_sigmoid(s[o] + b[r0 + o]);
}

// Stage one path's projections: wave wq computes rows [4wq,4wq+4) of each of
// the three 16-row projections, shares Y2/Z via LDS, writes its 8 XY
// products, and returns Z[8] in registers. Two __syncthreads inside.
__device__ __forceinline__ void stage_path(const float* __restrict__ Wx, const float* __restrict__ bx,
                                           const float* __restrict__ Wy, const float* __restrict__ by,
                                           const float* __restrict__ Wz, const float* __restrict__ bz,
                                           const float* __restrict__ xr, const float* __restrict__ yr,
                                           const float* __restrict__ zr,
                                           int wq, int lane,
                                           float* __restrict__ sY2, float* __restrict__ sZ,
                                           float* __restrict__ sXY, float Z[8]) {
    float t4[4];
    proj4(Wx, bx, xr, wq * 4, t4);
    const float X0 = fmaxf(t4[0], t4[1]);   // X[2wq]
    const float X1 = fmaxf(t4[2], t4[3]);   // X[2wq+1]
    proj4(Wy, by, yr, wq * 4, t4);
    sY2[wq * NS + lane] = fmaxf(fmaxf(t4[0], t4[1]), fmaxf(t4[2], t4[3]));  // Y2[wq]
    proj4(Wz, bz, zr, wq * 4, t4);
    sZ[(2 * wq) * NS + lane]     = fmaxf(t4[0], t4[1]);   // Z[2wq]
    sZ[(2 * wq + 1) * NS + lane] = fmaxf(t4[2], t4[3]);   // Z[2wq+1]
    __syncthreads();
    float y2[4];
    #pragma unroll
    for (int m = 0; m < 4; ++m) y2[m] = sY2[m * NS + lane];
    #pragma unroll
    for (int m = 0; m < 4; ++m) {
        sXY[((2 * wq) * 4 + m) * NS + lane]     = X0 * y2[m];
        sXY[((2 * wq + 1) * 4 + m) * NS + lane] = X1 * y2[m];
    }
    #pragma unroll
    for (int zz = 0; zz < 8; ++zz) Z[zz] = sZ[zz * NS + lane];
    __syncthreads();
}

// acc[k] = bias[16wq+k] + sum_q sum_ll XY[q]*Z[ll] * WT[(q*8+ll)*64 + 16wq+k]
__device__ __forceinline__ void fusion_part(const float* __restrict__ WT,
                                            const float* __restrict__ bias,
                                            int wq, int lane,
                                            const float* __restrict__ sXY,
                                            const float Z[8], float acc[16]) {
    #pragma unroll
    for (int k = 0; k < 16; ++k) acc[k] = bias[wq * 16 + k];
    #pragma unroll 1
    for (int q = 0; q < 32; ++q) {
        const float t = sXY[q * NS + lane];
        const float* wbase = WT + q * 8 * 64 + wq * 16;  // uniform -> s_load
        #pragma unroll
        for (int ll = 0; ll < 8; ++ll) {
            const float f = t * Z[ll];
            const float* w = wbase + ll * 64;
            #pragma unroll
            for (int k = 0; k < 16; ++k)
                acc[k] = fmaf(f, w[k], acc[k]);
        }
    }
}

// h[k] += sum_i sG[i][lane] * WngT[(roff+i)*64 + 16wq + k]
__device__ __forceinline__ void ng_part(const float* __restrict__ WngT, int roff,
                                        int wq, int lane,
                                        const float* __restrict__ sG, float h[16]) {
    #pragma unroll 4
    for (int i = 0; i < 64; ++i) {
        const float gi = sG[i * NS + lane];
        const float* w = WngT + (roff + i) * 64 + wq * 16;  // uniform -> s_load
        #pragma unroll
        for (int k = 0; k < 16; ++k)
            h[k] = fmaf(gi, w[k], h[k]);
    }
}

__global__ __launch_bounds__(NT, 4)
void fused_fwd(const float* __restrict__ a,  const float* __restrict__ v,
               const float* __restrict__ l,  const float* __restrict__ pa,
               const float* __restrict__ pv, const float* __restrict__ pl,
               const float* __restrict__ mean,
               const float* __restrict__ Wa,  const float* __restrict__ ba,
               const float* __restrict__ Wv,  const float* __restrict__ bv,
               const float* __restrict__ Wl,  const float* __restrict__ bl,
               const float* __restrict__ Wap, const float* __restrict__ bap,
               const float* __restrict__ Wvp, const float* __restrict__ bvp,
               const float* __restrict__ Wlp, const float* __restrict__ blp,
               const float* __restrict__ bf1, const float* __restrict__ bfp1,
               const float* __restrict__ bng,
               const float* __restrict__ rm1, const float* __restrict__ rm2,
               const float* __restrict__ WfT, const float* __restrict__ WfpT,
               const float* __restrict__ WngT,
               float* __restrict__ out) {
    __shared__ float sY2[4 * NS];
    __shared__ float sZ[8 * NS];
    __shared__ float sXY[32 * NS];
    __shared__ float sG[64 * NS];

    const int tid = threadIdx.x;
    const int lane = tid & 63;
    const int wq = __builtin_amdgcn_readfirstlane(tid >> 6);  // wave-uniform SGPR
    const int sample = blockIdx.x * NS + lane;
    const size_t base = (size_t)sample * 64;

    float Z[8], acc[16], h[16];

    // ---------------- path 2 (p_a, p_v, p_l) -> fusion_2 ----------------
    stage_path(Wap, bap, Wvp, bvp, Wlp, blp, pa + base, pv + base, pl + base,
               wq, lane, sY2, sZ, sXY, Z);
    fusion_part(WfpT, bfp1, wq, lane, sXY, Z, acc);

    // gate(lrelu(fusion_2), rm1[0:64]) -> sG rows [16wq,16wq+16)
    #pragma unroll
    for (int k = 0; k < 16; ++k)
        sG[(wq * 16 + k) * NS + lane] = gate(lrelu(acc[k]), rm1[wq * 16 + k]);
    __syncthreads();

    #pragma unroll
    for (int k = 0; k < 16; ++k) h[k] = bng[wq * 16 + k];
    ng_part(WngT, 0, wq, lane, sG, h);
    __syncthreads();  // all sG reads done before overwrite

    // gated mean -> sG (rows 64..127 of the Wng input)
    {
        const float4* m4 = reinterpret_cast<const float4*>(mean + base + wq * 16);
        #pragma unroll
        for (int c = 0; c < 4; ++c) {
            float4 t = m4[c];
            const int kk = wq * 16 + c * 4;
            sG[(kk + 0) * NS + lane] = gate(t.x, rm1[64 + kk + 0]);
            sG[(kk + 1) * NS + lane] = gate(t.y, rm1[64 + kk + 1]);
            sG[(kk + 2) * NS + lane] = gate(t.z, rm1[64 + kk + 2]);
            sG[(kk + 3) * NS + lane] = gate(t.w, rm1[64 + kk + 3]);
        }
    }
    __syncthreads();
    ng_part(WngT, 64, wq, lane, sG, h);

    // ---------------- path 1 (a, v, l) -> fusion_1 ----------------
    stage_path(Wa, ba, Wv, bv, Wl, bl, a + base, v + base, l + base,
               wq, lane, sY2, sZ, sXY, Z);
    fusion_part(WfT, bf1, wq, lane, sXY, Z, acc);

    // ---------------- epilogue ----------------
    // out[0:64] = gate(h, rm2[0:64]); out[64:128] = gate(lrelu(fusion_1), rm2[64:128])
    float4* o4a = reinterpret_cast<float4*>(out + (size_t)sample * 128 + wq * 16);
    #pragma unroll
    for (int c = 0; c < 4; ++c) {
        const int kk = wq * 16 + c * 4;
        float4 o;
        o.x = gate(h[c * 4 + 0], rm2[kk + 0]);
        o.y = gate(h[c * 4 + 1], rm2[kk + 1]);
        o.z = gate(h[c * 4 + 2], rm2[kk + 2]);
        o.w = gate(h[c * 4 + 3], rm2[kk + 3]);
        o4a[c] = o;
    }
    float4* o4b = reinterpret_cast<float4*>(out + (size_t)sample * 128 + 64 + wq * 16);
    #pragma unroll
    for (int c = 0; c < 4; ++c) {
        const int kk = wq * 16 + c * 4;
        float4 o;
        o.x = gate(lrelu(acc[c * 4 + 0]), rm2[64 + kk + 0]);
        o.y = gate(lrelu(acc[c * 4 + 1]), rm2[64 + kk + 1]);
        o.z = gate(lrelu(acc[c * 4 + 2]), rm2[64 + kk + 2]);
        o.w = gate(lrelu(acc[c * 4 + 3]), rm2[64 + kk + 3]);
        o4b[c] = o;
    }
}

// Pre-transpose Wf1 [64,256] -> WfT [256,64], Wfp1 likewise, Wng [64,128] ->
// WngT [128,64] so the main kernel's scalar weight loads are contiguous.
__global__ void transpose_w(const float* __restrict__ Wf1,
                            const float* __restrict__ Wfp1,
                            const float* __restrict__ Wng,
                            float* __restrict__ ws) {
    const int idx = blockIdx.x * 256 + threadIdx.x;
    if (idx < 16384) {
        const int j = idx >> 6, k = idx & 63;
        ws[idx] = Wf1[k * 256 + j];
    } else if (idx < 32768) {
        const int t = idx - 16384;
        const int j = t >> 6, k = t & 63;
        ws[16384 + t] = Wfp1[k * 256 + j];
    } else if (idx < 40960) {
        const int t = idx - 32768;
        const int i = t >> 6, k = t & 63;
        ws[32768 + t] = Wng[k * 128 + i];
    }
}

extern "C" void kernel_launch(void* const* d_in, const int* in_sizes, int n_in,
                              void* d_out, int out_size, void* d_ws, size_t ws_size,
                              hipStream_t stream) {
    const float* a    = (const float*)d_in[0];
    const float* v    = (const float*)d_in[1];
    const float* l    = (const float*)d_in[2];
    const float* pa   = (const float*)d_in[3];
    const float* pv   = (const float*)d_in[4];
    const float* pl   = (const float*)d_in[5];
    const float* mean = (const float*)d_in[6];
    const float* Wa   = (const float*)d_in[7];
    const float* ba   = (const float*)d_in[8];
    const float* Wv   = (const float*)d_in[9];
    const float* bv   = (const float*)d_in[10];
    const float* Wl   = (const float*)d_in[11];
    const float* bl   = (const float*)d_in[12];
    const float* Wap  = (const float*)d_in[13];
    const float* bap  = (const float*)d_in[14];
    const float* Wvp  = (const float*)d_in[15];
    const float* bvp  = (const float*)d_in[16];
    const float* Wlp  = (const float*)d_in[17];
    const float* blp  = (const float*)d_in[18];
    const float* Wf1  = (const float*)d_in[19];
    const float* bf1  = (const float*)d_in[20];
    const float* Wfp1 = (const float*)d_in[21];
    const float* bfp1 = (const float*)d_in[22];
    const float* Wng  = (const float*)d_in[23];
    const float* bng  = (const float*)d_in[24];
    const float* rm1  = (const float*)d_in[25];
    const float* rm2  = (const float*)d_in[26];

    float* ws = (float*)d_ws;  // needs 40960 floats = 160 KiB

    transpose_w<<<160, 256, 0, stream>>>(Wf1, Wfp1, Wng, ws);
    fused_fwd<<<65536 / NS, NT, 0, stream>>>(a, v, l, pa, pv, pl, mean,
                                             Wa, ba, Wv, bv, Wl, bl,
                                             Wap, bap, Wvp, bvp, Wlp, blp,
                                             bf1, bfp1, bng, rm1, rm2,
                                             ws, ws + 16384, ws + 32768,
                                             (float*)d_out);
}